// Round 3
// baseline (309.761 us; speedup 1.0000x reference)
//
#include <hip/hip_runtime.h>

// SSIM loss, N=64 images, 1 ch, 384x384 f32, 7x7 box window, VALID -> 378x378.
// out = -mean(S).
//
// R3: (1) vertical phase prefetches all 14 row-vectors into registers before
// accumulating (kills the serialized load->use->load chain that R2's VGPR=44
// betrayed), (2) SSIM formula multiplied through by 49^4 (integer-free of the
// 1/49 normalizations; q-scale already removed algebraically), (3) final
// reduction fused via last-block-done pattern (deterministic: fixed summation
// order; int atomic only gates who reduces).

constexpr int IND   = 384;
constexpr int OUTD  = 378;
constexpr int TH    = 32;    // output tile height
constexpr int TW    = 32;    // output tile width
constexpr int LDW   = 40;    // vs row stride (floats)
constexpr int TILES = 12;

using f32x4 = __attribute__((ext_vector_type(4))) float;
using f32x2 = __attribute__((ext_vector_type(2))) float;

__global__ __launch_bounds__(256, 4)
void ssim_fused(const float* __restrict__ X, const float* __restrict__ Y,
                const float* __restrict__ MX, float* __restrict__ blocksum,
                unsigned int* __restrict__ counter, float* __restrict__ out,
                int nblocks, float inv_npix)
{
    __shared__ float vs[5][TH][LDW];   // vertical 7-tap sums of {x, y, xx, yy, xy}
    __shared__ float wsum[4];
    __shared__ unsigned int slast;

    const int n   = blockIdx.z;
    const int tx  = blockIdx.x, ty = blockIdx.y;
    const int tid = threadIdx.x;
    const int row0 = ty * TH, col0 = tx * TW;

    const float* __restrict__ Xn = X + (size_t)n * (IND * IND);
    const float* __restrict__ Yn = Y + (size_t)n * (IND * IND);

    // ---- vertical 7-tap moment sums straight from global ----
    for (int idx = tid; idx < TH * 10; idx += 256) {
        const int r  = idx / 10;
        const int cg = idx - r * 10;
        const int gc = col0 + cg * 4;

        f32x4 xv[7], yv[7];

        if (gc + 3 < IND) {
            if (row0 + r + 6 < IND) {
                // fast path: issue all 14 loads back-to-back, then accumulate
                const float* px = &Xn[(row0 + r) * IND + gc];
                const float* py = &Yn[(row0 + r) * IND + gc];
#pragma unroll
                for (int k = 0; k < 7; ++k) {
                    xv[k] = *(const f32x4*)(px + k * IND);
                    yv[k] = *(const f32x4*)(py + k * IND);
                }
            } else {
                // bottom edge: clamped rows (feed masked outputs only)
#pragma unroll
                for (int k = 0; k < 7; ++k) {
                    int gr = row0 + r + k; if (gr > IND - 1) gr = IND - 1;
                    xv[k] = *(const f32x4*)&Xn[gr * IND + gc];
                    yv[k] = *(const f32x4*)&Yn[gr * IND + gc];
                }
            }
        } else {
            // right edge (tx==11, cg>=8): scalar column-clamped path
#pragma unroll
            for (int k = 0; k < 7; ++k) {
                int gr = row0 + r + k; if (gr > IND - 1) gr = IND - 1;
                const float* rx = &Xn[gr * IND];
                const float* ry = &Yn[gr * IND];
#pragma unroll
                for (int i = 0; i < 4; ++i) {
                    int c = gc + i; if (c > IND - 1) c = IND - 1;
                    xv[k][i] = rx[c];
                    yv[k][i] = ry[c];
                }
            }
        }

        f32x4 ax = 0.f, ay = 0.f, axx = 0.f, ayy = 0.f, axy = 0.f;
#pragma unroll
        for (int k = 0; k < 7; ++k) {
            ax  += xv[k];         ay  += yv[k];
            axx += xv[k] * xv[k]; ayy += yv[k] * yv[k]; axy += xv[k] * yv[k];
        }

        *(f32x4*)&vs[0][r][cg * 4] = ax;
        *(f32x4*)&vs[1][r][cg * 4] = ay;
        *(f32x4*)&vs[2][r][cg * 4] = axx;
        *(f32x4*)&vs[3][r][cg * 4] = ayy;
        *(f32x4*)&vs[4][r][cg * 4] = axy;
    }
    __syncthreads();

    // ---- horizontal sliding 7-tap + SSIM (scaled by 49^4: inv-free) ----
    const float m   = MX[n];
    const float c1  = (0.01f * m) * (0.01f * m);
    const float c2  = (0.03f * m) * (0.03f * m);
    const float k1  = 2401.0f * c1;      // 49^2 * C1
    const float k2  = 2401.0f * c2;      // 49^2 * C2
    const float cn  = 49.0f / 48.0f;
    const float cn2 = 2.0f * cn;

    const int r  = tid >> 3;          // 0..31
    const int cb = (tid & 7) * 4;     // 0,4,...,28

    float t0[10], t1[10], t2[10], t3[10], t4[10];
#define LOADT(T, Q)                                              \
    {                                                            \
        f32x4 a = *(const f32x4*)&vs[Q][r][cb];                  \
        f32x4 b = *(const f32x4*)&vs[Q][r][cb + 4];              \
        f32x2 c = *(const f32x2*)&vs[Q][r][cb + 8];              \
        T[0]=a.x; T[1]=a.y; T[2]=a.z; T[3]=a.w;                  \
        T[4]=b.x; T[5]=b.y; T[6]=b.z; T[7]=b.w;                  \
        T[8]=c.x; T[9]=c.y;                                      \
    }
    LOADT(t0, 0) LOADT(t1, 1) LOADT(t2, 2) LOADT(t3, 3) LOADT(t4, 4)
#undef LOADT

    float sx = 0.f, sy = 0.f, sxx = 0.f, syy = 0.f, sxy = 0.f;
#pragma unroll
    for (int k = 0; k < 7; ++k) {
        sx += t0[k]; sy += t1[k]; sxx += t2[k]; syy += t3[k]; sxy += t4[k];
    }

    float partial = 0.f;
    const int orow = row0 + r;
#pragma unroll
    for (int j = 0; j < 4; ++j) {
        if (j > 0) {
            sx  += t0[j + 6] - t0[j - 1];
            sy  += t1[j + 6] - t1[j - 1];
            sxx += t2[j + 6] - t2[j - 1];
            syy += t3[j + 6] - t3[j - 1];
            sxy += t4[j + 6] - t4[j - 1];
        }
        const int ocol = col0 + cb + j;
        if (orow < OUTD && ocol < OUTD) {
            float pxy = sx * sy;
            float ss  = sx * sx + sy * sy;
            float A1  = 2.0f * pxy + k1;
            float B1  = ss + k1;
            float t   = 49.0f * sxy - pxy;
            float A2  = cn2 * t + k2;
            float u   = 49.0f * (sxx + syy) - ss;
            float B2  = cn * u + k2;
            partial += __fdividef(A1 * A2, B1 * B2);
        }
    }

    // ---- block reduction (deterministic) ----
#pragma unroll
    for (int off = 32; off; off >>= 1) partial += __shfl_down(partial, off);
    if ((tid & 63) == 0) wsum[tid >> 6] = partial;
    __syncthreads();

    const int bid = ((int)n * TILES + ty) * TILES + tx;
    unsigned int prev = 0;
    if (tid == 0) {
        blocksum[bid] = wsum[0] + wsum[1] + wsum[2] + wsum[3];
        __threadfence();                       // publish blocksum (device scope)
        prev = atomicAdd(counter, 1u);
        slast = prev;
    }
    __syncthreads();

    // ---- last block folds all block sums (fixed order -> deterministic) ----
    if (slast == (unsigned int)(nblocks - 1)) {
        __threadfence();                       // acquire published blocksums
        float s = 0.f;
        for (int i = tid; i < nblocks; i += 256) s += blocksum[i];
#pragma unroll
        for (int off = 32; off; off >>= 1) s += __shfl_down(s, off);
        __syncthreads();                       // wsum reuse hazard
        if ((tid & 63) == 0) wsum[tid >> 6] = s;
        __syncthreads();
        if (tid == 0)
            out[0] = -(wsum[0] + wsum[1] + wsum[2] + wsum[3]) * inv_npix;
    }
}

extern "C" void kernel_launch(void* const* d_in, const int* in_sizes, int n_in,
                              void* d_out, int out_size, void* d_ws, size_t ws_size,
                              hipStream_t stream)
{
    const float* X  = (const float*)d_in[0];
    const float* Y  = (const float*)d_in[1];
    // d_in[2] = norm (unused by reference), d_in[4] = w (ones/49, baked in)
    const float* MX = (const float*)d_in[3];

    const int N       = in_sizes[3];                 // 64
    const int nblocks = N * TILES * TILES;           // 9216

    float* bs = (float*)d_ws;
    unsigned int* counter = (unsigned int*)((char*)d_ws + (size_t)nblocks * sizeof(float));

    hipMemsetAsync(counter, 0, sizeof(unsigned int), stream);

    const float inv_npix = 1.0f / ((float)N * OUTD * OUTD);
    dim3 grid(TILES, TILES, N);
    ssim_fused<<<grid, 256, 0, stream>>>(X, Y, MX, bs, counter, (float*)d_out,
                                         nblocks, inv_npix);
}

// Round 4
// 50.785 us; speedup vs baseline: 6.0994x; 6.0994x over previous
//
#include <hip/hip_runtime.h>

// SSIM loss, N=64 images, 1 ch, 384x384 f32, 7x7 box, VALID -> 378x378. out = -mean(S).
//
// R4: column-sliding-window design, zero LDS in the hot loop.
//  - Block = 7 waves (448 thr). Wave w owns cols 58w..58w+63 (6-col overlap);
//    lanes 0..57 produce output cols. Block covers a 21-output-row band.
//  - Each thread walks its column: running vertical sums of {x,y,xx,yy,xy}
//    (add row r+6, subtract row r-1 from a 7-deep register history, statically
//    indexed via 7-step unroll), ~16 VALU/row instead of 63.
//  - Horizontal 7-tap sums in-register via 4 __shfl_down per moment.
//  - Loads software-pipelined one row ahead (2 coalesced dwords per step).
//  - Two-kernel deterministic reduction (R3's fused atomic tail was the 6x
//    regression: single-line atomic + device fence serialized block retirement).

constexpr int IND   = 384;
constexpr int OUTD  = 378;
constexpr int RB    = 21;            // output rows per block (multiple of 7)
constexpr int BANDS = OUTD / RB;     // 18
constexpr int NT    = 448;           // 7 waves

__device__ __forceinline__ float hsum7(float v) {
    // sum of v over lanes l..l+6
    float d1 = v + __shfl_down(v, 1);        // v_l + v_{l+1}
    float d2 = d1 + __shfl_down(d1, 2);      // v_l..v_{l+3}
    return d2 + __shfl_down(d1, 4) + __shfl_down(v, 6);
}

__global__ __launch_bounds__(NT, 4)
void ssim_col(const float* __restrict__ X, const float* __restrict__ Y,
              const float* __restrict__ MX, float* __restrict__ blocksum)
{
    const int band = blockIdx.x;
    const int n    = blockIdx.y;
    const int wave = threadIdx.x >> 6;
    const int lane = threadIdx.x & 63;

    const int ocol = wave * 58 + lane;         // output col this thread produces
    int col = ocol; if (col > IND - 1) col = IND - 1;   // clamped load col
    const int r0 = band * RB;                  // inputs r0..r0+26 (always in range)

    const float* __restrict__ Xc = X + (size_t)n * (IND * IND) + col;
    const float* __restrict__ Yc = Y + (size_t)n * (IND * IND) + col;

    // ---- init: rows r0..r0+5 into history, row r0+6 into the pipeline regs ----
    float hx0 = Xc[(size_t)(r0 + 0) * IND], hy0 = Yc[(size_t)(r0 + 0) * IND];
    float hx1 = Xc[(size_t)(r0 + 1) * IND], hy1 = Yc[(size_t)(r0 + 1) * IND];
    float hx2 = Xc[(size_t)(r0 + 2) * IND], hy2 = Yc[(size_t)(r0 + 2) * IND];
    float hx3 = Xc[(size_t)(r0 + 3) * IND], hy3 = Yc[(size_t)(r0 + 3) * IND];
    float hx4 = Xc[(size_t)(r0 + 4) * IND], hy4 = Yc[(size_t)(r0 + 4) * IND];
    float hx5 = Xc[(size_t)(r0 + 5) * IND], hy5 = Yc[(size_t)(r0 + 5) * IND];
    float nx  = Xc[(size_t)(r0 + 6) * IND], ny  = Yc[(size_t)(r0 + 6) * IND];
    float hx6 = 0.f, hy6 = 0.f;   // written at step 0 before first read (step 6)

    float sx  = hx0 + hx1 + hx2 + hx3 + hx4 + hx5;
    float sy  = hy0 + hy1 + hy2 + hy3 + hy4 + hy5;
    float sxx = hx0*hx0 + hx1*hx1 + hx2*hx2 + hx3*hx3 + hx4*hx4 + hx5*hx5;
    float syy = hy0*hy0 + hy1*hy1 + hy2*hy2 + hy3*hy3 + hy4*hy4 + hy5*hy5;
    float sxy = hx0*hy0 + hx1*hy1 + hx2*hy2 + hx3*hy3 + hx4*hy4 + hx5*hy5;

    const float m   = MX[n];
    const float c1  = (0.01f * m) * (0.01f * m);
    const float c2  = (0.03f * m) * (0.03f * m);
    const float k1  = 2401.0f * c1;        // 49^2 * C1
    const float k2  = 2401.0f * c2;
    const float cn  = 49.0f / 48.0f;
    const float cn2 = 2.0f * cn;

    const bool valid = (lane <= 57) && (ocol <= OUTD - 1);
    float partial = 0.f;
    int rload = r0 + 7;                    // next row to prefetch

    // step j: old row (r0+j) in slot j%7; new row (r0+j+6) goes to slot (j+6)%7
#define STEP(HRX, HRY, HWX, HWY)                                        \
    {                                                                   \
        sx += nx; sy += ny;                                             \
        sxx = fmaf(nx, nx, sxx);                                        \
        syy = fmaf(ny, ny, syy);                                        \
        sxy = fmaf(nx, ny, sxy);                                        \
        const float ox = HRX, oy = HRY;                                 \
        HWX = nx; HWY = ny;                                             \
        int nr = rload; if (nr > IND - 1) nr = IND - 1;                 \
        nx = Xc[(size_t)nr * IND]; ny = Yc[(size_t)nr * IND];           \
        ++rload;                                                        \
        float t1 = hsum7(sx);                                           \
        float t2 = hsum7(sy);                                           \
        float t3 = hsum7(sxx);                                          \
        float t4 = hsum7(syy);                                          \
        float t5 = hsum7(sxy);                                          \
        float pxy = t1 * t2;                                            \
        float ss  = fmaf(t1, t1, t2 * t2);                              \
        float A1  = fmaf(2.f, pxy, k1);                                 \
        float B1  = ss + k1;                                            \
        float A2  = fmaf(cn2, fmaf(49.f, t5, -pxy), k2);                \
        float B2  = fmaf(cn, fmaf(49.f, t3 + t4, -ss), k2);             \
        if (valid) partial += __fdividef(A1 * A2, B1 * B2);             \
        sx -= ox; sy -= oy;                                             \
        sxx = fmaf(-ox, ox, sxx);                                       \
        syy = fmaf(-oy, oy, syy);                                       \
        sxy = fmaf(-ox, oy, sxy);                                       \
    }

    for (int k = 0; k < RB / 7; ++k) {
        STEP(hx0, hy0, hx6, hy6)   // j%7==0: read slot0, write slot6
        STEP(hx1, hy1, hx0, hy0)
        STEP(hx2, hy2, hx1, hy1)
        STEP(hx3, hy3, hx2, hy2)
        STEP(hx4, hy4, hx3, hy3)
        STEP(hx5, hy5, hx4, hy4)
        STEP(hx6, hy6, hx5, hy5)
    }
#undef STEP

    // ---- block reduction (deterministic, no atomics) ----
#pragma unroll
    for (int off = 32; off; off >>= 1) partial += __shfl_down(partial, off);

    __shared__ float wsum[7];
    if (lane == 0) wsum[wave] = partial;
    __syncthreads();
    if (threadIdx.x == 0) {
        float s = 0.f;
#pragma unroll
        for (int w = 0; w < 7; ++w) s += wsum[w];
        blocksum[(size_t)n * BANDS + band] = s;
    }
}

__global__ __launch_bounds__(256)
void ssim_reduce(const float* __restrict__ blocksum, float* __restrict__ out,
                 int nblocks, float inv_npix)
{
    const int tid = threadIdx.x;
    float s = 0.f;
    for (int i = tid; i < nblocks; i += 256) s += blocksum[i];
#pragma unroll
    for (int off = 32; off; off >>= 1) s += __shfl_down(s, off);
    __shared__ float ws[4];
    if ((tid & 63) == 0) ws[tid >> 6] = s;
    __syncthreads();
    if (tid == 0) out[0] = -(ws[0] + ws[1] + ws[2] + ws[3]) * inv_npix;
}

extern "C" void kernel_launch(void* const* d_in, const int* in_sizes, int n_in,
                              void* d_out, int out_size, void* d_ws, size_t ws_size,
                              hipStream_t stream)
{
    const float* X  = (const float*)d_in[0];
    const float* Y  = (const float*)d_in[1];
    // d_in[2] = norm (unused by reference), d_in[4] = w (ones/49, baked in)
    const float* MX = (const float*)d_in[3];

    const int N       = in_sizes[3];             // 64
    const int nblocks = N * BANDS;               // 1152

    float* bs = (float*)d_ws;                    // 4.6 KB of block sums

    dim3 grid(BANDS, N);
    ssim_col<<<grid, NT, 0, stream>>>(X, Y, MX, bs);

    const float inv_npix = 1.0f / ((float)N * OUTD * OUTD);
    ssim_reduce<<<1, 256, 0, stream>>>(bs, (float*)d_out, nblocks, inv_npix);
}

// Round 5
// 30.181 us; speedup vs baseline: 10.2634x; 1.6827x over previous
//
#include <hip/hip_runtime.h>

// SSIM loss, N=64 images, 1 ch, 384x384 f32, 7x7 box, VALID -> 378x378. out = -mean(S).
//
// R5: register-resident band walker.
//  - Block = 1 wave (64 thr). Lane l owns cols 6l..6l+5 (64*6 = 384: full width,
//    no lane waste, no column clamping). Band = 14 output rows; 27 bands x 64 imgs
//    = 1728 blocks.
//  - Vertical {x,y,xx,yy,xy} sums slide in registers (7-deep raw history,
//    statically indexed by 7-step unroll). ~10 VALU per col per row.
//  - Horizontal 7-tap: local sliding sum over own 6 cols + 6 INDEPENDENT
//    depth-1 __shfl_down(.,1) per moment (R4 had 20 chained shuffles/px; now 5/px).
//  - Loads: 3x float2 per array per row, software-pipelined 2 rows ahead
//    (~500 cy own-wave cover >> L2/L3 latency).
//  - All loads in-bounds by construction (rows r0..r0+19 <= 383, cols 0..383).
//    Only lane 63's outputs (cols 378..383) are masked; it still feeds lane 62's
//    shuffles. Lane 62's valid outputs need at most col 377+6=383 = lane63 v5. OK.

constexpr int IND   = 384;
constexpr int OUTD  = 378;
constexpr int RB    = 14;            // output rows per band
constexpr int BANDS = OUTD / RB;     // 27
constexpr int CPL   = 6;             // cols per lane

using f32x2 = __attribute__((ext_vector_type(2))) float;

__global__ __launch_bounds__(64, 2)
void ssim_band(const float* __restrict__ X, const float* __restrict__ Y,
               const float* __restrict__ MX, float* __restrict__ blocksum)
{
    const int band = blockIdx.x;
    const int n    = blockIdx.y;
    const int lane = threadIdx.x;
    const int c0   = lane * CPL;
    const int r0   = band * RB;      // input rows r0..r0+19, all <= 383

    const float* __restrict__ Xp = X + (size_t)n * (IND * IND) + c0;
    const float* __restrict__ Yp = Y + (size_t)n * (IND * IND) + c0;

    float hx[7][CPL], hy[7][CPL];                  // raw 7-row history
    float sx[CPL]  = {}, sy[CPL]  = {};
    float sxx[CPL] = {}, syy[CPL] = {}, sxy[CPL] = {};

#define LOADROW(DX, DY, R) {                                                  \
    const float* _px = Xp + (size_t)(R) * IND;                                \
    const float* _py = Yp + (size_t)(R) * IND;                                \
    f32x2 _a = *(const f32x2*)_px;                                            \
    f32x2 _b = *(const f32x2*)(_px + 2);                                      \
    f32x2 _c = *(const f32x2*)(_px + 4);                                      \
    f32x2 _d = *(const f32x2*)_py;                                            \
    f32x2 _e = *(const f32x2*)(_py + 2);                                      \
    f32x2 _f = *(const f32x2*)(_py + 4);                                      \
    DX[0]=_a.x; DX[1]=_a.y; DX[2]=_b.x; DX[3]=_b.y; DX[4]=_c.x; DX[5]=_c.y;   \
    DY[0]=_d.x; DY[1]=_d.y; DY[2]=_e.x; DY[3]=_e.y; DY[4]=_f.x; DY[5]=_f.y; }

    // ---- prologue: rows r0..r0+6 into history, prefetch r0+7, r0+8 ----
#pragma unroll
    for (int k = 0; k < 7; ++k) LOADROW(hx[k], hy[k], r0 + k)

    float pax[CPL], pay[CPL], pbx[CPL], pby[CPL];
    LOADROW(pax, pay, r0 + 7)
    LOADROW(pbx, pby, r0 + 8)

#pragma unroll
    for (int k = 0; k < 7; ++k)
#pragma unroll
        for (int c = 0; c < CPL; ++c) {
            float x = hx[k][c], y = hy[k][c];
            sx[c] += x;  sy[c] += y;
            sxx[c] = fmaf(x, x, sxx[c]);
            syy[c] = fmaf(y, y, syy[c]);
            sxy[c] = fmaf(x, y, sxy[c]);
        }

    const float m   = MX[n];
    const float c1  = (0.01f * m) * (0.01f * m);
    const float c2  = (0.03f * m) * (0.03f * m);
    const float k1  = 2401.0f * c1;      // 49^2 * C1
    const float k2  = 2401.0f * c2;
    const float cn  = 49.0f / 48.0f;
    const float cn2 = 2.0f * cn;

    // horizontal sliding sum: O[i] = sum over window cols (6l+i .. 6l+i+6)
#define HSUM(S, O) {                                                          \
    float _n0 = __shfl_down(S[0], 1), _n1 = __shfl_down(S[1], 1);             \
    float _n2 = __shfl_down(S[2], 1), _n3 = __shfl_down(S[3], 1);             \
    float _n4 = __shfl_down(S[4], 1), _n5 = __shfl_down(S[5], 1);             \
    float _t  = ((S[0]+S[1]) + (S[2]+S[3])) + (S[4]+S[5]);                    \
    O[0] = _t   + _n0;                                                        \
    O[1] = O[0] - S[0] + _n1;                                                 \
    O[2] = O[1] - S[1] + _n2;                                                 \
    O[3] = O[2] - S[2] + _n3;                                                 \
    O[4] = O[3] - S[3] + _n4;                                                 \
    O[5] = O[4] - S[4] + _n5; }

    float partial = 0.f;

    for (int kk = 0; kk < RB / 7; ++kk) {
#pragma unroll
        for (int i = 0; i < 7; ++i) {
            // ---- horizontal sums + formula for output row r0 + 7*kk + i ----
            float t1[CPL], t2[CPL], t3[CPL], t4[CPL], t5[CPL];
            HSUM(sx,  t1) HSUM(sy,  t2) HSUM(sxx, t3) HSUM(syy, t4) HSUM(sxy, t5)

            if (lane < 63) {
#pragma unroll
                for (int c = 0; c < CPL; ++c) {
                    float pxy = t1[c] * t2[c];
                    float ss  = fmaf(t1[c], t1[c], t2[c] * t2[c]);
                    float A1  = fmaf(2.f, pxy, k1);
                    float B1  = ss + k1;
                    float A2  = fmaf(cn2, fmaf(49.f, t5[c], -pxy), k2);
                    float B2  = fmaf(cn, fmaf(49.f, t3[c] + t4[c], -ss), k2);
                    partial += __fdividef(A1 * A2, B1 * B2);
                }
            }

            // ---- slide: -row(r0+j) +row(r0+j+7); refill 2-deep pipeline ----
#pragma unroll
            for (int c = 0; c < CPL; ++c) {
                float nx = pax[c], ny = pay[c];
                float ox = hx[i][c], oy = hy[i][c];
                sx[c] += nx - ox;
                sy[c] += ny - oy;
                sxx[c] = fmaf(nx, nx, fmaf(-ox, ox, sxx[c]));
                syy[c] = fmaf(ny, ny, fmaf(-oy, oy, syy[c]));
                sxy[c] = fmaf(nx, ny, fmaf(-ox, oy, sxy[c]));
                hx[i][c] = nx;  hy[i][c] = ny;
                pax[c] = pbx[c]; pay[c] = pby[c];
            }
            int nr = r0 + 7 * kk + i + 9;          // 2 rows ahead
            if (nr > IND - 1) nr = IND - 1;        // tail: harmless clamped load
            LOADROW(pbx, pby, nr)
        }
    }
#undef HSUM
#undef LOADROW

    // ---- wave reduction (deterministic) ----
#pragma unroll
    for (int off = 32; off; off >>= 1) partial += __shfl_down(partial, off);
    if (lane == 0) blocksum[(size_t)n * BANDS + band] = partial;
}

__global__ __launch_bounds__(256)
void ssim_reduce(const float* __restrict__ blocksum, float* __restrict__ out,
                 int nblocks, float inv_npix)
{
    const int tid = threadIdx.x;
    float s = 0.f;
    for (int i = tid; i < nblocks; i += 256) s += blocksum[i];
#pragma unroll
    for (int off = 32; off; off >>= 1) s += __shfl_down(s, off);
    __shared__ float ws[4];
    if ((tid & 63) == 0) ws[tid >> 6] = s;
    __syncthreads();
    if (tid == 0) out[0] = -(ws[0] + ws[1] + ws[2] + ws[3]) * inv_npix;
}

extern "C" void kernel_launch(void* const* d_in, const int* in_sizes, int n_in,
                              void* d_out, int out_size, void* d_ws, size_t ws_size,
                              hipStream_t stream)
{
    const float* X  = (const float*)d_in[0];
    const float* Y  = (const float*)d_in[1];
    // d_in[2] = norm (unused by reference), d_in[4] = w (ones/49, baked in)
    const float* MX = (const float*)d_in[3];

    const int N       = in_sizes[3];             // 64
    const int nblocks = N * BANDS;               // 1728

    float* bs = (float*)d_ws;

    dim3 grid(BANDS, N);
    ssim_band<<<grid, 64, 0, stream>>>(X, Y, MX, bs);

    const float inv_npix = 1.0f / ((float)N * OUTD * OUTD);
    ssim_reduce<<<1, 256, 0, stream>>>(bs, (float*)d_out, nblocks, inv_npix);
}